// Round 4
// baseline (34025.235 us; speedup 1.0000x reference)
//
#include <hip/hip_runtime.h>
#include <hip/hip_bf16.h>

#define NC 4096
#define NSTEP 2500

typedef float v4f __attribute__((ext_vector_type(4)));
typedef short v8s __attribute__((ext_vector_type(8)));
typedef unsigned long long u64;

// ws layout (bytes):
//   [0,1024)        tags[256] (int)         -- step counters per CU
//   [1024,1088)     accum[16] (float)       -- readout partial sums
//   [4096,69632)    ring[2][4][4096] bf16   -- double-buffered r broadcast
#define WS_WORDS 17408  // zero first 69632 bytes

__device__ __forceinline__ short f2bf_s(float f) {
  __hip_bfloat16 h = __float2bfloat16(f);
  return __bfloat16_as_short(h);
}

__device__ __forceinline__ unsigned pack_bf2(float a, float b) {
  unsigned ua = (unsigned short)f2bf_s(a);
  unsigned ub = (unsigned short)f2bf_s(b);
  return ua | (ub << 16);
}

__global__ void rnn_init(unsigned* ws_u) {
  int i = blockIdx.x * blockDim.x + threadIdx.x;
  if (i < WS_WORDS) ws_u[i] = 0u;
}

__global__ __launch_bounds__(512, 2) void rnn_persist(
    const float* __restrict__ x, const float* __restrict__ rec_w,
    const float* __restrict__ rec_b, const float* __restrict__ inp_w,
    const float* __restrict__ out_w, const float* __restrict__ mem_w,
    const float* __restrict__ noise, float* __restrict__ ws) {
  const int cu   = blockIdx.x;       // 0..255, owns rows [cu*16, cu*16+16)
  const int tid  = threadIdx.x;
  const int wave = tid >> 6;         // 0..7, K-slice [wave*512, +512)
  const int lane = tid & 63;
  const int n    = lane & 15;        // MFMA col (batch; valid < 4) / A row
  const int g    = lane >> 4;        // quad
  const int row0 = cu << 4;

  int* tags             = (int*)ws;
  float* accum          = ws + 256;
  __hip_bfloat16* ring  = (__hip_bfloat16*)(ws + 1024);

  __shared__ v4f red[8][64];                 // 8 KB: cross-wave K reduction
  __shared__ unsigned short rbuf[4 * NC];    // 32 KB: staged bf16 r_t [b][k]

  // ---- W A-fragments in VGPRs: lane holds W[row0+n][k = wave*512+f*32+g*8+j]
  v8s wfrag[16];
  {
    const float* wp = rec_w + (size_t)(row0 + n) * NC + wave * 512 + g * 8;
#pragma unroll
    for (int f = 0; f < 16; ++f) {
      const float* p = wp + f * 32;
      float4 a = *(const float4*)p;
      float4 b = *(const float4*)(p + 4);
      v8s w;
      w[0] = f2bf_s(a.x); w[1] = f2bf_s(a.y); w[2] = f2bf_s(a.z); w[3] = f2bf_s(a.w);
      w[4] = f2bf_s(b.x); w[5] = f2bf_s(b.y); w[6] = f2bf_s(b.z); w[7] = f2bf_s(b.w);
      wfrag[f] = w;
    }
  }

  // ---- master (wave 0) per-lane state: rows row0+4g+q, col b=n&3
  float rst[4] = {0, 0, 0, 0}, tmem[4] = {0, 0, 0, 0}, tout[4] = {0, 0, 0, 0};
  float bias[4] = {0, 0, 0, 0}, esmp[4] = {0, 0, 0, 0}, etst[4] = {0, 0, 0, 0};
  if (wave == 0) {
    float4 bb = *(const float4*)(rec_b + row0 + g * 4);
    bias[0] = bb.x; bias[1] = bb.y; bias[2] = bb.z; bias[3] = bb.w;
    const int b = n & 3;
    float xs0 = x[b * 4 + 0], xs1 = x[b * 4 + 1];
    float xt0 = x[b * 4 + 2], xt1 = x[b * 4 + 3];
#pragma unroll
    for (int q = 0; q < 4; ++q) {
      int i = row0 + g * 4 + q;
      float w0 = inp_w[2 * i], w1 = inp_w[2 * i + 1];
      esmp[q] = xs0 * w0 + xs1 * w1;
      etst[q] = xt0 * w0 + xt1 * w1;
    }
  }

  const int tagbase = lane * 4;
  for (int t = 0; t < NSTEP; ++t) {
    const int slot = t & 1;
    if (wave == 0) {
      // tags[c] >= t  <=>  CU c published r_t (sc1 atomics -> MALL, coherent)
      int guard = 0;
      while (true) {
        int a0 = __hip_atomic_load(&tags[tagbase + 0], __ATOMIC_RELAXED, __HIP_MEMORY_SCOPE_AGENT);
        int a1 = __hip_atomic_load(&tags[tagbase + 1], __ATOMIC_RELAXED, __HIP_MEMORY_SCOPE_AGENT);
        int a2 = __hip_atomic_load(&tags[tagbase + 2], __ATOMIC_RELAXED, __HIP_MEMORY_SCOPE_AGENT);
        int a3 = __hip_atomic_load(&tags[tagbase + 3], __ATOMIC_RELAXED, __HIP_MEMORY_SCOPE_AGENT);
        bool ok = (a0 >= t) & (a1 >= t) & (a2 >= t) & (a3 >= t);
        if (__all(ok)) break;
        if (++guard > (1 << 24)) break;  // anti-hang safety valve
      }
      __builtin_amdgcn_fence(__ATOMIC_ACQUIRE, "agent");
    }
    __syncthreads();

    // ---- stage r_t into LDS via agent-scope (sc1 -> MALL) atomic loads.
    {
      const u64* ring64 = (const u64*)(ring + (size_t)slot * 4 * NC);
      u64* lds64 = (u64*)rbuf;
#pragma unroll
      for (int i = 0; i < 8; ++i) {
        int idx = tid + i * 512;  // 4096 u64 = 32 KB
        lds64[idx] = __hip_atomic_load(&ring64[idx], __ATOMIC_RELAXED,
                                       __HIP_MEMORY_SCOPE_AGENT);
      }
    }
    __syncthreads();

    // ---- B-fragments from LDS: lane holds r[b=n&3][k = wave*512+f*32+g*8+j]
    const unsigned short* rb = rbuf + (n & 3) * NC + wave * 512 + g * 8;
    v4f acc = {0.f, 0.f, 0.f, 0.f};
#pragma unroll
    for (int f = 0; f < 16; ++f) {
      v8s bfr = *(const v8s*)(rb + f * 32);
      acc = __builtin_amdgcn_mfma_f32_16x16x32_bf16(wfrag[f], bfr, acc, 0, 0, 0);
    }
    red[wave][lane] = acc;
    __syncthreads();

    if (wave == 0) {
      v4f s = red[0][lane];
#pragma unroll
      for (int w = 1; w < 8; ++w) s += red[w][lane];
      float4 nz = *(const float4*)(noise + (size_t)t * NC + row0 + g * 4);
      const int ph = t / 500;  // 0 fix, 1 sample, 2 delay, 3 test, 4 response
#pragma unroll
      for (int q = 0; q < 4; ++q) {
        float e = (ph == 1) ? esmp[q] : ((ph == 3) ? etst[q] : 0.f);
        float pre = s[q] + bias[q] + e;
        float rl = pre > 0.f ? pre : 0.f;
        float nq = (q == 0) ? nz.x : (q == 1) ? nz.y : (q == 2) ? nz.z : nz.w;
        rst[q] = 0.8f * rst[q] + 0.2f * rl + 0.02f * nq;
      }
      if (t >= 1000 && t < 1500) {
#pragma unroll
        for (int q = 0; q < 4; ++q) tmem[q] += rst[q];
      }
      if (t >= 2000) {
#pragma unroll
        for (int q = 0; q < 4; ++q) tout[q] += rst[q];
      }
      if (n < 4) {  // publish bf16 chunk via sc1 atomic store -> MALL
        u64 v = (u64)pack_bf2(rst[0], rst[1]) |
                ((u64)pack_bf2(rst[2], rst[3]) << 32);
        u64* dst = (u64*)(ring + ((size_t)(slot ^ 1) * 4 + n) * NC + row0 + g * 4);
        __hip_atomic_store(dst, v, __ATOMIC_RELAXED, __HIP_MEMORY_SCOPE_AGENT);
      }
      __builtin_amdgcn_fence(__ATOMIC_RELEASE, "agent");
      if (lane == 0)
        __hip_atomic_store(&tags[cu], t + 1, __ATOMIC_RELEASE,
                           __HIP_MEMORY_SCOPE_AGENT);
    }
  }

  // ---- readout partials: out[s][b][o] += sum_i w[o][i] * tsum[b][i]
  if (wave == 0) {
    float pm0 = 0, pm1 = 0, po0 = 0, po1 = 0;
#pragma unroll
    for (int q = 0; q < 4; ++q) {
      int i = row0 + g * 4 + q;
      pm0 += mem_w[i] * tmem[q];
      pm1 += mem_w[NC + i] * tmem[q];
      po0 += out_w[i] * tout[q];
      po1 += out_w[NC + i] * tout[q];
    }
    pm0 += __shfl_xor(pm0, 16); pm0 += __shfl_xor(pm0, 32);
    pm1 += __shfl_xor(pm1, 16); pm1 += __shfl_xor(pm1, 32);
    po0 += __shfl_xor(po0, 16); po0 += __shfl_xor(po0, 32);
    po1 += __shfl_xor(po1, 16); po1 += __shfl_xor(po1, 32);
    if (lane < 4) {
      atomicAdd(&accum[lane * 2 + 0], pm0);
      atomicAdd(&accum[lane * 2 + 1], pm1);
      atomicAdd(&accum[8 + lane * 2 + 0], po0);
      atomicAdd(&accum[8 + lane * 2 + 1], po1);
    }
  }
}

// Output is FLOAT32 (reference returns f32) — 16 floats, not bf16!
__global__ void rnn_final(const float* __restrict__ ws, float* __restrict__ out) {
  int i = threadIdx.x;
  if (i < 16) out[i] = ws[256 + i] * (1.0f / 500.0f);
}

extern "C" void kernel_launch(void* const* d_in, const int* in_sizes, int n_in,
                              void* d_out, int out_size, void* d_ws, size_t ws_size,
                              hipStream_t stream) {
  (void)in_sizes; (void)n_in; (void)out_size; (void)ws_size;
  const float* x     = (const float*)d_in[0];
  const float* rec_w = (const float*)d_in[1];
  const float* rec_b = (const float*)d_in[2];
  const float* inp_w = (const float*)d_in[3];
  const float* out_w = (const float*)d_in[4];
  const float* mem_w = (const float*)d_in[5];
  const float* noise = (const float*)d_in[6];
  float* ws = (float*)d_ws;

  rnn_init<<<(WS_WORDS + 255) / 256, 256, 0, stream>>>((unsigned*)d_ws);
  rnn_persist<<<256, 512, 0, stream>>>(x, rec_w, rec_b, inp_w, out_w, mem_w,
                                       noise, ws);
  rnn_final<<<1, 64, 0, stream>>>(ws, (float*)d_out);
}

// Round 5
// 27469.507 us; speedup vs baseline: 1.2387x; 1.2387x over previous
//
#include <hip/hip_runtime.h>
#include <hip/hip_bf16.h>

#define NC 4096
#define NSTEP 2500

typedef float v4f __attribute__((ext_vector_type(4)));
typedef short v8s __attribute__((ext_vector_type(8)));
typedef unsigned long long u64;

// ws layout (bytes):
//   [0,1024)        cnt[4 slots][4 subs], each padded to 64 B (16 u32)
//   [1024,1088)     accum[16] (float)    -- readout partial sums
//   [4096,69632)    ring[2][4][4096] bf16 -- double-buffered r broadcast
#define WS_WORDS 17408  // zero first 69632 bytes

__device__ __forceinline__ short f2bf_s(float f) {
  __hip_bfloat16 h = __float2bfloat16(f);
  return __bfloat16_as_short(h);
}

__device__ __forceinline__ unsigned pack_bf2(float a, float b) {
  unsigned ua = (unsigned short)f2bf_s(a);
  unsigned ub = (unsigned short)f2bf_s(b);
  return ua | (ub << 16);
}

__global__ void rnn_init(unsigned* ws_u) {
  int i = blockIdx.x * blockDim.x + threadIdx.x;
  // pre-publish r_0 = zeros: slot-0 sub-counters (words 0,16,32,48) start at 64
  if (i < WS_WORDS) ws_u[i] = (i < 64 && (i & 15) == 0) ? 64u : 0u;
}

__global__ __launch_bounds__(512, 2) void rnn_persist(
    const float* __restrict__ x, const float* __restrict__ rec_w,
    const float* __restrict__ rec_b, const float* __restrict__ inp_w,
    const float* __restrict__ out_w, const float* __restrict__ mem_w,
    const float* __restrict__ noise, float* __restrict__ ws) {
  const int cu   = blockIdx.x;       // 0..255, owns rows [cu*16, cu*16+16)
  const int tid  = threadIdx.x;
  const int wave = tid >> 6;         // 0..7, K-slice [wave*512, +512)
  const int lane = tid & 63;
  const int n    = lane & 15;        // MFMA col (batch; valid < 4) / A row
  const int g    = lane >> 4;        // quad; also staging batch index
  const int j16  = lane & 15;        // staging chunk index
  const int row0 = cu << 4;

  unsigned* cnt        = (unsigned*)ws;
  float* accum         = ws + 256;
  __hip_bfloat16* ring = (__hip_bfloat16*)(ws + 1024);

  __shared__ unsigned short rbuf[8 * 2048];  // 32 KB: [wave][b][512] bf16
  __shared__ v4f red[8][64];                 // 8 KB: cross-wave K reduction

  // ---- W A-fragments in VGPRs: lane holds W[row0+n][k = wave*512+f*32+g*8+j]
  v8s wfrag[16];
  {
    const float* wp = rec_w + (size_t)(row0 + n) * NC + wave * 512 + g * 8;
#pragma unroll
    for (int f = 0; f < 16; ++f) {
      const float* p = wp + f * 32;
      float4 a = *(const float4*)p;
      float4 b = *(const float4*)(p + 4);
      v8s w;
      w[0] = f2bf_s(a.x); w[1] = f2bf_s(a.y); w[2] = f2bf_s(a.z); w[3] = f2bf_s(a.w);
      w[4] = f2bf_s(b.x); w[5] = f2bf_s(b.y); w[6] = f2bf_s(b.z); w[7] = f2bf_s(b.w);
      wfrag[f] = w;
    }
  }

  // ---- wave0 per-lane state: rows row0+4g+q, batch b=n&3
  float rst[4] = {0, 0, 0, 0}, tmem[4] = {0, 0, 0, 0}, tout[4] = {0, 0, 0, 0};
  float bias[4] = {0, 0, 0, 0}, esmp[4] = {0, 0, 0, 0}, etst[4] = {0, 0, 0, 0};
  if (wave == 0) {
    float4 bb = *(const float4*)(rec_b + row0 + g * 4);
    bias[0] = bb.x; bias[1] = bb.y; bias[2] = bb.z; bias[3] = bb.w;
    const int b = n & 3;
    float xs0 = x[b * 4 + 0], xs1 = x[b * 4 + 1];
    float xt0 = x[b * 4 + 2], xt1 = x[b * 4 + 3];
#pragma unroll
    for (int q = 0; q < 4; ++q) {
      int i = row0 + g * 4 + q;
      float w0 = inp_w[2 * i], w1 = inp_w[2 * i + 1];
      esmp[q] = xs0 * w0 + xs1 * w1;
      etst[q] = xt0 * w0 + xt1 * w1;
    }
  }

  for (int t = 0; t < NSTEP; ++t) {
    const int slot = t & 1;
    float4 nz = {0.f, 0.f, 0.f, 0.f};
    if (wave == 0) {
      // prefetch noise early; latency hides under poll discovery
      nz = *(const float4*)(noise + (size_t)t * NC + row0 + g * 4);
      // wait for all 256 CUs to have published r_t (4 padded sub-counters)
      const unsigned thr = (unsigned)((t >> 2) + 1) << 6;
      const unsigned* cp = cnt + (((t & 3) * 4 + (lane & 3)) << 4);
      int guard = 0;
      while (true) {
        unsigned v = (lane < 4)
                         ? __hip_atomic_load(cp, __ATOMIC_RELAXED,
                                             __HIP_MEMORY_SCOPE_AGENT)
                         : thr;
        if (__all(v >= thr)) break;
        if (++guard > (1 << 22)) break;  // anti-hang safety valve
      }
      __builtin_amdgcn_fence(__ATOMIC_ACQUIRE, "agent");  // inv L1/L2
    }
    __syncthreads();  // release all waves: r_t readable via plain loads

    // ---- stage own 4-KB K-slice (plain loads: MALL once/XCD, L2 after)
    {
      const v8s* gsrc =
          (const v8s*)(ring + ((size_t)slot * 4 + g) * NC + wave * 512);
      v8s* ldst = (v8s*)(rbuf + wave * 2048 + g * 512);
#pragma unroll
      for (int i = 0; i < 4; ++i) ldst[j16 + 16 * i] = gsrc[j16 + 16 * i];
    }
    __syncthreads();  // intra-CU: staging visible to all lanes

    // ---- B-fragments from own wave's LDS region
    const unsigned short* rb = rbuf + wave * 2048 + (n & 3) * 512 + g * 8;
    v4f acc = {0.f, 0.f, 0.f, 0.f};
#pragma unroll
    for (int f = 0; f < 16; ++f) {
      v8s bfr = *(const v8s*)(rb + f * 32);
      acc = __builtin_amdgcn_mfma_f32_16x16x32_bf16(wfrag[f], bfr, acc, 0, 0, 0);
    }
    red[wave][lane] = acc;
    __syncthreads();

    if (wave == 0) {
      v4f s = red[0][lane];
#pragma unroll
      for (int w = 1; w < 8; ++w) s += red[w][lane];
      const int ph = t / 500;  // 0 fix, 1 sample, 2 delay, 3 test, 4 response
#pragma unroll
      for (int q = 0; q < 4; ++q) {
        float e = (ph == 1) ? esmp[q] : ((ph == 3) ? etst[q] : 0.f);
        float pre = s[q] + bias[q] + e;
        float rl = pre > 0.f ? pre : 0.f;
        float nq = (q == 0) ? nz.x : (q == 1) ? nz.y : (q == 2) ? nz.z : nz.w;
        rst[q] = 0.8f * rst[q] + 0.2f * rl + 0.02f * nq;
      }
      if (t >= 1000 && t < 1500) {
#pragma unroll
        for (int q = 0; q < 4; ++q) tmem[q] += rst[q];
      }
      if (t >= 2000) {
#pragma unroll
        for (int q = 0; q < 4; ++q) tout[q] += rst[q];
      }
      if (n < 4) {  // publish r_{t+1} chunk (plain store; fence makes visible)
        u64 v = (u64)pack_bf2(rst[0], rst[1]) |
                ((u64)pack_bf2(rst[2], rst[3]) << 32);
        *(u64*)(ring + ((size_t)((t + 1) & 1) * 4 + n) * NC + row0 + g * 4) = v;
      }
      __builtin_amdgcn_fence(__ATOMIC_RELEASE, "agent");  // drain + wbl2
      if (lane == 0) {
        unsigned* ap = cnt + ((((t + 1) & 3) * 4 + (cu & 3)) << 4);
        __hip_atomic_fetch_add(ap, 1u, __ATOMIC_RELAXED,
                               __HIP_MEMORY_SCOPE_AGENT);
      }
    }
  }

  // ---- readout partials: out[s][b][o] += sum_i w[o][i] * tsum[b][i]
  if (wave == 0) {
    float pm0 = 0, pm1 = 0, po0 = 0, po1 = 0;
#pragma unroll
    for (int q = 0; q < 4; ++q) {
      int i = row0 + g * 4 + q;
      pm0 += mem_w[i] * tmem[q];
      pm1 += mem_w[NC + i] * tmem[q];
      po0 += out_w[i] * tout[q];
      po1 += out_w[NC + i] * tout[q];
    }
    pm0 += __shfl_xor(pm0, 16); pm0 += __shfl_xor(pm0, 32);
    pm1 += __shfl_xor(pm1, 16); pm1 += __shfl_xor(pm1, 32);
    po0 += __shfl_xor(po0, 16); po0 += __shfl_xor(po0, 32);
    po1 += __shfl_xor(po1, 16); po1 += __shfl_xor(po1, 32);
    if (lane < 4) {
      atomicAdd(&accum[lane * 2 + 0], pm0);
      atomicAdd(&accum[lane * 2 + 1], pm1);
      atomicAdd(&accum[8 + lane * 2 + 0], po0);
      atomicAdd(&accum[8 + lane * 2 + 1], po1);
    }
  }
}

// Output is FLOAT32 (reference returns f32)
__global__ void rnn_final(const float* __restrict__ ws, float* __restrict__ out) {
  int i = threadIdx.x;
  if (i < 16) out[i] = ws[256 + i] * (1.0f / 500.0f);
}

extern "C" void kernel_launch(void* const* d_in, const int* in_sizes, int n_in,
                              void* d_out, int out_size, void* d_ws, size_t ws_size,
                              hipStream_t stream) {
  (void)in_sizes; (void)n_in; (void)out_size; (void)ws_size;
  const float* x     = (const float*)d_in[0];
  const float* rec_w = (const float*)d_in[1];
  const float* rec_b = (const float*)d_in[2];
  const float* inp_w = (const float*)d_in[3];
  const float* out_w = (const float*)d_in[4];
  const float* mem_w = (const float*)d_in[5];
  const float* noise = (const float*)d_in[6];
  float* ws = (float*)d_ws;

  rnn_init<<<(WS_WORDS + 255) / 256, 256, 0, stream>>>((unsigned*)d_ws);
  rnn_persist<<<256, 512, 0, stream>>>(x, rec_w, rec_b, inp_w, out_w, mem_w,
                                       noise, ws);
  rnn_final<<<1, 64, 0, stream>>>(ws, (float*)d_out);
}

// Round 6
// 14402.666 us; speedup vs baseline: 2.3624x; 1.9073x over previous
//
#include <hip/hip_runtime.h>
#include <hip/hip_bf16.h>

#define NC 4096
#define NSTEP 2500

typedef float v4f __attribute__((ext_vector_type(4)));
typedef short v8s __attribute__((ext_vector_type(8)));
typedef unsigned long long u64;

// ws layout (bytes):
//   [0,1024)        cnt[4 slots][4 subs], each padded to 64 B (16 u32)
//   [1024,1088)     accum[16] (float)    -- readout partial sums
//   [4096,69632)    ring[2][4][4096] bf16 -- double-buffered r broadcast
#define WS_WORDS 17408  // zero first 69632 bytes

__device__ __forceinline__ short f2bf_s(float f) {
  __hip_bfloat16 h = __float2bfloat16(f);
  return __bfloat16_as_short(h);
}

__device__ __forceinline__ unsigned pack_bf2(float a, float b) {
  unsigned ua = (unsigned short)f2bf_s(a);
  unsigned ub = (unsigned short)f2bf_s(b);
  return ua | (ub << 16);
}

__global__ void rnn_init(unsigned* ws_u) {
  int i = blockIdx.x * blockDim.x + threadIdx.x;
  // pre-publish r_0 = zeros: slot-0 sub-counters (words 0,16,32,48) start at 64
  if (i < WS_WORDS) ws_u[i] = (i < 64 && (i & 15) == 0) ? 64u : 0u;
}

__global__ __launch_bounds__(512, 2) void rnn_persist(
    const float* __restrict__ x, const float* __restrict__ rec_w,
    const float* __restrict__ rec_b, const float* __restrict__ inp_w,
    const float* __restrict__ out_w, const float* __restrict__ mem_w,
    const float* __restrict__ noise, float* __restrict__ ws) {
  const int cu   = blockIdx.x;       // 0..255, owns rows [cu*16, cu*16+16)
  const int tid  = threadIdx.x;
  const int wave = tid >> 6;         // 0..7, K-slice [wave*512, +512)
  const int lane = tid & 63;
  const int n    = lane & 15;        // MFMA col (batch; valid < 4) / A row
  const int g    = lane >> 4;        // quad
  const int row0 = cu << 4;

  unsigned* cnt        = (unsigned*)ws;
  float* accum         = ws + 256;
  __hip_bfloat16* ring = (__hip_bfloat16*)(ws + 1024);

  __shared__ unsigned short rbuf[4 * NC];    // 32 KB: staged bf16 r_t [b][k]
  __shared__ v4f red[8][64];                 // 8 KB: cross-wave K reduction

  // ---- W A-fragments in VGPRs: lane holds W[row0+n][k = wave*512+f*32+g*8+j]
  v8s wfrag[16];
  {
    const float* wp = rec_w + (size_t)(row0 + n) * NC + wave * 512 + g * 8;
#pragma unroll
    for (int f = 0; f < 16; ++f) {
      const float* p = wp + f * 32;
      float4 a = *(const float4*)p;
      float4 b = *(const float4*)(p + 4);
      v8s w;
      w[0] = f2bf_s(a.x); w[1] = f2bf_s(a.y); w[2] = f2bf_s(a.z); w[3] = f2bf_s(a.w);
      w[4] = f2bf_s(b.x); w[5] = f2bf_s(b.y); w[6] = f2bf_s(b.z); w[7] = f2bf_s(b.w);
      wfrag[f] = w;
    }
  }

  // ---- wave0 per-lane state: rows row0+4g+q, batch b=n&3
  float rst[4] = {0, 0, 0, 0}, tmem[4] = {0, 0, 0, 0}, tout[4] = {0, 0, 0, 0};
  float bias[4] = {0, 0, 0, 0}, esmp[4] = {0, 0, 0, 0}, etst[4] = {0, 0, 0, 0};
  if (wave == 0) {
    float4 bb = *(const float4*)(rec_b + row0 + g * 4);
    bias[0] = bb.x; bias[1] = bb.y; bias[2] = bb.z; bias[3] = bb.w;
    const int b = n & 3;
    float xs0 = x[b * 4 + 0], xs1 = x[b * 4 + 1];
    float xt0 = x[b * 4 + 2], xt1 = x[b * 4 + 3];
#pragma unroll
    for (int q = 0; q < 4; ++q) {
      int i = row0 + g * 4 + q;
      float w0 = inp_w[2 * i], w1 = inp_w[2 * i + 1];
      esmp[q] = xs0 * w0 + xs1 * w1;
      etst[q] = xt0 * w0 + xt1 * w1;
    }
  }

  for (int t = 0; t < NSTEP; ++t) {
    const int slot = t & 1;
    float4 nz = {0.f, 0.f, 0.f, 0.f};
    if (wave == 0) {
      // prefetch noise early; latency hides under poll discovery
      nz = *(const float4*)(noise + (size_t)t * NC + row0 + g * 4);
      // wait for all 256 CUs to have published r_t (4 padded sub-counters)
      const unsigned thr = (unsigned)((t >> 2) + 1) << 6;
      const unsigned* cp = cnt + (((t & 3) * 4 + (lane & 3)) << 4);
      int guard = 0;
      while (true) {
        unsigned v = (lane < 4)
                         ? __hip_atomic_load(cp, __ATOMIC_RELAXED,
                                             __HIP_MEMORY_SCOPE_AGENT)
                         : thr;
        if (__all(v >= thr)) break;
        if (++guard > (1 << 22)) break;  // anti-hang safety valve
      }
      // NO acquire fence: ring is read below via sc1 loads (MALL-coherent)
    }
    __syncthreads();

    // ---- stage r_t into LDS via sc1 u64 atomic loads (bypass L1/L2, no inv)
    {
      const u64* ring64 = (const u64*)(ring + (size_t)slot * 4 * NC);
      u64* lds64 = (u64*)rbuf;
#pragma unroll
      for (int i = 0; i < 8; ++i) {
        int idx = tid + i * 512;  // 4096 u64 = 32 KB
        lds64[idx] = __hip_atomic_load(&ring64[idx], __ATOMIC_RELAXED,
                                       __HIP_MEMORY_SCOPE_AGENT);
      }
    }
    __syncthreads();

    // ---- B-fragments from LDS: lane holds r[b=n&3][k = wave*512+f*32+g*8+j]
    const unsigned short* rb = rbuf + (n & 3) * NC + wave * 512 + g * 8;
    v4f acc = {0.f, 0.f, 0.f, 0.f};
#pragma unroll
    for (int f = 0; f < 16; ++f) {
      v8s bfr = *(const v8s*)(rb + f * 32);
      acc = __builtin_amdgcn_mfma_f32_16x16x32_bf16(wfrag[f], bfr, acc, 0, 0, 0);
    }
    red[wave][lane] = acc;
    __syncthreads();

    if (wave == 0) {
      v4f s = red[0][lane];
#pragma unroll
      for (int w = 1; w < 8; ++w) s += red[w][lane];
      const int ph = t / 500;  // 0 fix, 1 sample, 2 delay, 3 test, 4 response
#pragma unroll
      for (int q = 0; q < 4; ++q) {
        float e = (ph == 1) ? esmp[q] : ((ph == 3) ? etst[q] : 0.f);
        float pre = s[q] + bias[q] + e;
        float rl = pre > 0.f ? pre : 0.f;
        float nq = (q == 0) ? nz.x : (q == 1) ? nz.y : (q == 2) ? nz.z : nz.w;
        rst[q] = 0.8f * rst[q] + 0.2f * rl + 0.02f * nq;
      }
      if (t >= 1000 && t < 1500) {
#pragma unroll
        for (int q = 0; q < 4; ++q) tmem[q] += rst[q];
      }
      if (t >= 2000) {
#pragma unroll
        for (int q = 0; q < 4; ++q) tout[q] += rst[q];
      }
      if (n < 4) {  // publish r_{t+1} chunk: sc1 write-through store -> MALL
        u64 v = (u64)pack_bf2(rst[0], rst[1]) |
                ((u64)pack_bf2(rst[2], rst[3]) << 32);
        u64* dst =
            (u64*)(ring + ((size_t)((t + 1) & 1) * 4 + n) * NC + row0 + g * 4);
        __hip_atomic_store(dst, v, __ATOMIC_RELAXED, __HIP_MEMORY_SCOPE_AGENT);
      }
      // order publish (write-through, complete at MALL when vmcnt retires)
      // before the counter bump -- no buffer_wbl2 needed, no fence.
      __builtin_amdgcn_s_waitcnt(0x0f70);  // vmcnt(0) only
      if (lane == 0) {
        unsigned* ap = cnt + ((((t + 1) & 3) * 4 + (cu & 3)) << 4);
        __hip_atomic_fetch_add(ap, 1u, __ATOMIC_RELAXED,
                               __HIP_MEMORY_SCOPE_AGENT);
      }
    }
  }

  // ---- readout partials: out[s][b][o] += sum_i w[o][i] * tsum[b][i]
  if (wave == 0) {
    float pm0 = 0, pm1 = 0, po0 = 0, po1 = 0;
#pragma unroll
    for (int q = 0; q < 4; ++q) {
      int i = row0 + g * 4 + q;
      pm0 += mem_w[i] * tmem[q];
      pm1 += mem_w[NC + i] * tmem[q];
      po0 += out_w[i] * tout[q];
      po1 += out_w[NC + i] * tout[q];
    }
    pm0 += __shfl_xor(pm0, 16); pm0 += __shfl_xor(pm0, 32);
    pm1 += __shfl_xor(pm1, 16); pm1 += __shfl_xor(pm1, 32);
    po0 += __shfl_xor(po0, 16); po0 += __shfl_xor(po0, 32);
    po1 += __shfl_xor(po1, 16); po1 += __shfl_xor(po1, 32);
    if (lane < 4) {
      atomicAdd(&accum[lane * 2 + 0], pm0);
      atomicAdd(&accum[lane * 2 + 1], pm1);
      atomicAdd(&accum[8 + lane * 2 + 0], po0);
      atomicAdd(&accum[8 + lane * 2 + 1], po1);
    }
  }
}

// Output is FLOAT32 (reference returns f32)
__global__ void rnn_final(const float* __restrict__ ws, float* __restrict__ out) {
  int i = threadIdx.x;
  if (i < 16) out[i] = ws[256 + i] * (1.0f / 500.0f);
}

extern "C" void kernel_launch(void* const* d_in, const int* in_sizes, int n_in,
                              void* d_out, int out_size, void* d_ws, size_t ws_size,
                              hipStream_t stream) {
  (void)in_sizes; (void)n_in; (void)out_size; (void)ws_size;
  const float* x     = (const float*)d_in[0];
  const float* rec_w = (const float*)d_in[1];
  const float* rec_b = (const float*)d_in[2];
  const float* inp_w = (const float*)d_in[3];
  const float* out_w = (const float*)d_in[4];
  const float* mem_w = (const float*)d_in[5];
  const float* noise = (const float*)d_in[6];
  float* ws = (float*)d_ws;

  rnn_init<<<(WS_WORDS + 255) / 256, 256, 0, stream>>>((unsigned*)d_ws);
  rnn_persist<<<256, 512, 0, stream>>>(x, rec_w, rec_b, inp_w, out_w, mem_w,
                                       noise, ws);
  rnn_final<<<1, 64, 0, stream>>>(ws, (float*)d_out);
}

// Round 7
// 11973.952 us; speedup vs baseline: 2.8416x; 1.2028x over previous
//
#include <hip/hip_runtime.h>
#include <hip/hip_bf16.h>

#define NC 4096
#define NSTEP 2500

typedef float v4f __attribute__((ext_vector_type(4)));
typedef short v8s __attribute__((ext_vector_type(8)));
typedef unsigned long long u64;

// ws layout (bytes):
//   [0,16384)       tags[256], each padded to a 64-B line (word idx cu*16)
//   [16384,16448)   accum[16] (float)     -- readout partial sums
//   [20480,86016)   ring[2][4][4096] bf16 -- double-buffered r broadcast
#define WS_WORDS 21504  // zero first 86016 bytes

__device__ __forceinline__ short f2bf_s(float f) {
  __hip_bfloat16 h = __float2bfloat16(f);
  return __bfloat16_as_short(h);
}

__device__ __forceinline__ unsigned pack_bf2(float a, float b) {
  unsigned ua = (unsigned short)f2bf_s(a);
  unsigned ub = (unsigned short)f2bf_s(b);
  return ua | (ub << 16);
}

__global__ void rnn_init(unsigned* ws_u) {
  int i = blockIdx.x * blockDim.x + threadIdx.x;
  // tags all 0 == "r_0 published" (reader gate at step t is tags[c] >= t)
  if (i < WS_WORDS) ws_u[i] = 0u;
}

__global__ __launch_bounds__(512, 2) void rnn_persist(
    const float* __restrict__ x, const float* __restrict__ rec_w,
    const float* __restrict__ rec_b, const float* __restrict__ inp_w,
    const float* __restrict__ out_w, const float* __restrict__ mem_w,
    const float* __restrict__ noise, float* __restrict__ ws) {
  const int cu   = blockIdx.x;       // 0..255, owns rows [cu*16, cu*16+16)
  const int tid  = threadIdx.x;
  const int wave = tid >> 6;         // 0..7, K-slice [wave*512, +512)
  const int lane = tid & 63;
  const int n    = lane & 15;        // MFMA col (batch; valid < 4) / A row
  const int g    = lane >> 4;        // quad
  const int row0 = cu << 4;

  unsigned* tags       = (unsigned*)ws;          // padded: tag c at word c*16
  float* accum         = ws + 4096;
  __hip_bfloat16* ring = (__hip_bfloat16*)(ws + 5120);

  __shared__ unsigned short rbuf[4 * NC];    // 32 KB: staged bf16 r_t [b][k]
  __shared__ v4f red[8][64];                 // 8 KB: cross-wave K reduction

  // ---- W A-fragments in VGPRs: lane holds W[row0+n][k = wave*512+f*32+g*8+j]
  v8s wfrag[16];
  {
    const float* wp = rec_w + (size_t)(row0 + n) * NC + wave * 512 + g * 8;
#pragma unroll
    for (int f = 0; f < 16; ++f) {
      const float* p = wp + f * 32;
      float4 a = *(const float4*)p;
      float4 b = *(const float4*)(p + 4);
      v8s w;
      w[0] = f2bf_s(a.x); w[1] = f2bf_s(a.y); w[2] = f2bf_s(a.z); w[3] = f2bf_s(a.w);
      w[4] = f2bf_s(b.x); w[5] = f2bf_s(b.y); w[6] = f2bf_s(b.z); w[7] = f2bf_s(b.w);
      wfrag[f] = w;
    }
  }

  // ---- wave0 per-lane state: rows row0+4g+q, batch b=n&3
  float rst[4] = {0, 0, 0, 0}, tmem[4] = {0, 0, 0, 0}, tout[4] = {0, 0, 0, 0};
  float bias[4] = {0, 0, 0, 0}, esmp[4] = {0, 0, 0, 0}, etst[4] = {0, 0, 0, 0};
  if (wave == 0) {
    float4 bb = *(const float4*)(rec_b + row0 + g * 4);
    bias[0] = bb.x; bias[1] = bb.y; bias[2] = bb.z; bias[3] = bb.w;
    const int b = n & 3;
    float xs0 = x[b * 4 + 0], xs1 = x[b * 4 + 1];
    float xt0 = x[b * 4 + 2], xt1 = x[b * 4 + 3];
#pragma unroll
    for (int q = 0; q < 4; ++q) {
      int i = row0 + g * 4 + q;
      float w0 = inp_w[2 * i], w1 = inp_w[2 * i + 1];
      esmp[q] = xs0 * w0 + xs1 * w1;
      etst[q] = xt0 * w0 + xt1 * w1;
    }
  }

  const int tagbase = lane * 4;  // this lane guards tags[tagbase..+3]
  for (int t = 0; t < NSTEP; ++t) {
    const int slot = t & 1;
    float4 nz = {0.f, 0.f, 0.f, 0.f};
    if (wave == 0) {
      // prefetch noise early; latency hides under poll discovery
      nz = *(const float4*)(noise + (size_t)t * NC + row0 + g * 4);
      // wait until every CU has published r_t (per-CU padded tag lines,
      // plain sc1 stores on the producer side -- no RMW serialization)
      const unsigned thr = (unsigned)t;
      int guard = 0;
      while (true) {
        unsigned a0 = __hip_atomic_load(tags + ((tagbase + 0) << 4),
                                        __ATOMIC_RELAXED, __HIP_MEMORY_SCOPE_AGENT);
        unsigned a1 = __hip_atomic_load(tags + ((tagbase + 1) << 4),
                                        __ATOMIC_RELAXED, __HIP_MEMORY_SCOPE_AGENT);
        unsigned a2 = __hip_atomic_load(tags + ((tagbase + 2) << 4),
                                        __ATOMIC_RELAXED, __HIP_MEMORY_SCOPE_AGENT);
        unsigned a3 = __hip_atomic_load(tags + ((tagbase + 3) << 4),
                                        __ATOMIC_RELAXED, __HIP_MEMORY_SCOPE_AGENT);
        bool ok = (a0 >= thr) & (a1 >= thr) & (a2 >= thr) & (a3 >= thr);
        if (__all(ok)) break;
        if (++guard > (1 << 22)) break;  // anti-hang safety valve
      }
      // NO acquire fence: ring is read below via sc1 loads (MALL-coherent)
    }
    __syncthreads();

    // ---- stage r_t into LDS via sc1 u64 atomic loads (bypass L1/L2, no inv)
    {
      const u64* ring64 = (const u64*)(ring + (size_t)slot * 4 * NC);
      u64* lds64 = (u64*)rbuf;
#pragma unroll
      for (int i = 0; i < 8; ++i) {
        int idx = tid + i * 512;  // 4096 u64 = 32 KB
        lds64[idx] = __hip_atomic_load(&ring64[idx], __ATOMIC_RELAXED,
                                       __HIP_MEMORY_SCOPE_AGENT);
      }
    }
    __syncthreads();

    // ---- B-fragments from LDS: lane holds r[b=n&3][k = wave*512+f*32+g*8+j]
    const unsigned short* rb = rbuf + (n & 3) * NC + wave * 512 + g * 8;
    v4f acc = {0.f, 0.f, 0.f, 0.f};
#pragma unroll
    for (int f = 0; f < 16; ++f) {
      v8s bfr = *(const v8s*)(rb + f * 32);
      acc = __builtin_amdgcn_mfma_f32_16x16x32_bf16(wfrag[f], bfr, acc, 0, 0, 0);
    }
    red[wave][lane] = acc;
    __syncthreads();

    if (wave == 0) {
      v4f s = red[0][lane];
#pragma unroll
      for (int w = 1; w < 8; ++w) s += red[w][lane];
      const int ph = t / 500;  // 0 fix, 1 sample, 2 delay, 3 test, 4 response
#pragma unroll
      for (int q = 0; q < 4; ++q) {
        float e = (ph == 1) ? esmp[q] : ((ph == 3) ? etst[q] : 0.f);
        float pre = s[q] + bias[q] + e;
        float rl = pre > 0.f ? pre : 0.f;
        float nq = (q == 0) ? nz.x : (q == 1) ? nz.y : (q == 2) ? nz.z : nz.w;
        rst[q] = 0.8f * rst[q] + 0.2f * rl + 0.02f * nq;
      }
      if (t >= 1000 && t < 1500) {
#pragma unroll
        for (int q = 0; q < 4; ++q) tmem[q] += rst[q];
      }
      if (t >= 2000) {
#pragma unroll
        for (int q = 0; q < 4; ++q) tout[q] += rst[q];
      }
      if (n < 4) {  // publish r_{t+1} chunk: sc1 write-through store -> MALL
        u64 v = (u64)pack_bf2(rst[0], rst[1]) |
                ((u64)pack_bf2(rst[2], rst[3]) << 32);
        u64* dst =
            (u64*)(ring + ((size_t)((t + 1) & 1) * 4 + n) * NC + row0 + g * 4);
        __hip_atomic_store(dst, v, __ATOMIC_RELAXED, __HIP_MEMORY_SCOPE_AGENT);
      }
      // order publish (write-through, complete at MALL when vmcnt retires)
      // before the tag store -- no cache maintenance, no RMW.
      __builtin_amdgcn_s_waitcnt(0x0f70);  // vmcnt(0) only
      if (lane == 0) {
        __hip_atomic_store(tags + (cu << 4), (unsigned)(t + 1),
                           __ATOMIC_RELAXED, __HIP_MEMORY_SCOPE_AGENT);
      }
    }
  }

  // ---- readout partials: out[s][b][o] += sum_i w[o][i] * tsum[b][i]
  if (wave == 0) {
    float pm0 = 0, pm1 = 0, po0 = 0, po1 = 0;
#pragma unroll
    for (int q = 0; q < 4; ++q) {
      int i = row0 + g * 4 + q;
      pm0 += mem_w[i] * tmem[q];
      pm1 += mem_w[NC + i] * tmem[q];
      po0 += out_w[i] * tout[q];
      po1 += out_w[NC + i] * tout[q];
    }
    pm0 += __shfl_xor(pm0, 16); pm0 += __shfl_xor(pm0, 32);
    pm1 += __shfl_xor(pm1, 16); pm1 += __shfl_xor(pm1, 32);
    po0 += __shfl_xor(po0, 16); po0 += __shfl_xor(po0, 32);
    po1 += __shfl_xor(po1, 16); po1 += __shfl_xor(po1, 32);
    if (lane < 4) {
      atomicAdd(&accum[lane * 2 + 0], pm0);
      atomicAdd(&accum[lane * 2 + 1], pm1);
      atomicAdd(&accum[8 + lane * 2 + 0], po0);
      atomicAdd(&accum[8 + lane * 2 + 1], po1);
    }
  }
}

// Output is FLOAT32 (reference returns f32)
__global__ void rnn_final(const float* __restrict__ ws, float* __restrict__ out) {
  int i = threadIdx.x;
  if (i < 16) out[i] = ws[4096 + i] * (1.0f / 500.0f);
}

extern "C" void kernel_launch(void* const* d_in, const int* in_sizes, int n_in,
                              void* d_out, int out_size, void* d_ws, size_t ws_size,
                              hipStream_t stream) {
  (void)in_sizes; (void)n_in; (void)out_size; (void)ws_size;
  const float* x     = (const float*)d_in[0];
  const float* rec_w = (const float*)d_in[1];
  const float* rec_b = (const float*)d_in[2];
  const float* inp_w = (const float*)d_in[3];
  const float* out_w = (const float*)d_in[4];
  const float* mem_w = (const float*)d_in[5];
  const float* noise = (const float*)d_in[6];
  float* ws = (float*)d_ws;

  rnn_init<<<(WS_WORDS + 255) / 256, 256, 0, stream>>>((unsigned*)d_ws);
  rnn_persist<<<256, 512, 0, stream>>>(x, rec_w, rec_b, inp_w, out_w, mem_w,
                                       noise, ws);
  rnn_final<<<1, 64, 0, stream>>>(ws, (float*)d_out);
}